// Round 1
// baseline (6315.579 us; speedup 1.0000x reference)
//
#include <hip/hip_runtime.h>
#include <hip/hip_bf16.h>
#include <stdint.h>

// ---------------------------------------------------------------------------
// NeighborhoodConsensus: out = net(x) + P(net(P(x)))  with P = swap spatial
// pairs (W,X)<->(Y,Z).  Equivariance: P(net(P(x);W)) = net(x; P_w(W)), where
// P_w permutes kernel taps (kw,kx,ky,kz)->(ky,kz,kw,kx).  So we run ONE
// network with 2 "branches" (normal / tap-permuted weights) on the same
// input, and sum after the final ReLU.  No tensor transposes at all.
//
// Layouts:
//   x   : fp32  [n][pos]               (C_in = 1), pos = w*13824+xx*576+y*24+z
//   y1  : bf16  [n][br][pos][16ci]     channels-last, 32 B/row
//   y2  : bf16  [n][br][pos][16ci]
//   out : fp32  [n][pos]
// Round-1 implementation: direct conv on the fp32 VALU (baseline).
// ---------------------------------------------------------------------------

#define S   24
#define S2  576
#define S3  13824
#define S4  331776

__device__ __forceinline__ float bflo(uint32_t u) { return __uint_as_float(u << 16); }
__device__ __forceinline__ float bfhi(uint32_t u) { return __uint_as_float(u & 0xFFFF0000u); }
__device__ __forceinline__ uint32_t f2bf(float f) {            // RNE f32->bf16
    uint32_t u = __float_as_uint(f);
    return (u + 0x7FFFu + ((u >> 16) & 1u)) >> 16;
}
__device__ __forceinline__ int permtap(int t) {                // (kw,kx,ky,kz)->(ky,kz,kw,kx)
    int kw = t / 27, kx = (t / 9) % 3, ky = (t / 3) % 3, kz = t % 3;
    return ky * 27 + kz * 9 + kw * 3 + kx;
}

// Pack weights: Wp1[t][br][co] f32 ; Wp2[br][t][ci][co] f32 ; Wp3[br][t][ci] f32
__global__ void prep_weights(const float* __restrict__ w1, const float* __restrict__ w2,
                             const float* __restrict__ w3,
                             float* __restrict__ Wp1, float* __restrict__ Wp2,
                             float* __restrict__ Wp3) {
    int tid = threadIdx.x;
    for (int i = tid; i < 81 * 32; i += 256) {
        int t = i >> 5, r = i & 31, br = r >> 4, co = r & 15;
        int tp = br ? permtap(t) : t;
        Wp1[i] = w1[co * 81 + tp];
    }
    for (int i = tid; i < 2 * 81 * 256; i += 256) {
        int co = i & 15, ci = (i >> 4) & 15, t = (i >> 8) % 81, br = i / (81 * 256);
        int tp = br ? permtap(t) : t;
        Wp2[i] = w2[(co * 16 + ci) * 81 + tp];
    }
    for (int i = tid; i < 2 * 81 * 16; i += 256) {
        int ci = i & 15, t = (i >> 4) % 81, br = i / (81 * 16);
        int tp = br ? permtap(t) : t;
        Wp3[i] = w3[ci * 81 + tp];
    }
}

// conv1: x (1ch fp32) -> y1 (16ch bf16) per branch.  Thread: 4 z-pos x 16 co.
__global__ __launch_bounds__(256) void conv1_kernel(
    const float* __restrict__ x, const float* __restrict__ Wp1,
    const float* __restrict__ b1, uint32_t* __restrict__ y1) {
    __shared__ float Wl[81 * 16];
    const int tid = threadIdx.x, idx = blockIdx.x;
    const int pgblk = idx % 324, br = (idx / 324) & 1, n = idx / 648;
    for (int i = tid; i < 81 * 16; i += 256) {
        int t = i >> 4, co = i & 15;
        Wl[i] = Wp1[t * 32 + br * 16 + co];
    }
    __syncthreads();
    const int pg = pgblk * 256 + tid;
    const int zb = (pg % 6) * 4, y = (pg / 6) % 24, xx = (pg / 144) % 24, w = pg / 3456;
    const float* xn = x + (size_t)n * S4;

    float acc[64];
#pragma unroll
    for (int i = 0; i < 64; ++i) acc[i] = 0.f;

#pragma unroll 1
    for (int dw = 0; dw < 3; ++dw) {
        int wsrc = w + dw - 1; bool okw = (unsigned)wsrc < 24u;
#pragma unroll 1
        for (int dx = 0; dx < 3; ++dx) {
            int xsrc = xx + dx - 1; bool okx = okw && (unsigned)xsrc < 24u;
#pragma unroll 1
            for (int dy = 0; dy < 3; ++dy) {
                int ysrc = y + dy - 1; bool oky = okx && (unsigned)ysrc < 24u;
                int rowb = wsrc * S3 + xsrc * S2 + ysrc * S;
#pragma unroll
                for (int dz = 0; dz < 3; ++dz) {
                    int t = dw * 27 + dx * 9 + dy * 3 + dz;
                    float xv[4];
#pragma unroll
                    for (int j = 0; j < 4; ++j) {
                        int zsrc = zb + j + dz - 1;
                        bool ok = oky && (unsigned)zsrc < 24u;
                        xv[j] = ok ? xn[rowb + zsrc] : 0.f;
                    }
#pragma unroll
                    for (int co = 0; co < 16; ++co) {
                        float wv = Wl[t * 16 + co];
#pragma unroll
                        for (int j = 0; j < 4; ++j)
                            acc[j * 16 + co] = fmaf(xv[j], wv, acc[j * 16 + co]);
                    }
                }
            }
        }
    }
    // epilogue: +bias, relu, pack bf16, store
    uint32_t* yb = y1 + (size_t)(n * 2 + br) * S4 * 8;
    const int pos = w * S3 + xx * S2 + y * S + zb;
#pragma unroll
    for (int j = 0; j < 4; ++j) {
        uint32_t pk[8];
#pragma unroll
        for (int cp = 0; cp < 8; ++cp) {
            float a = fmaxf(acc[j * 16 + 2 * cp]     + b1[2 * cp],     0.f);
            float b = fmaxf(acc[j * 16 + 2 * cp + 1] + b1[2 * cp + 1], 0.f);
            pk[cp] = f2bf(a) | (f2bf(b) << 16);
        }
        uint32_t* dst = yb + (size_t)(pos + j) * 8;
        *(uint4*)(dst)     = make_uint4(pk[0], pk[1], pk[2], pk[3]);
        *(uint4*)(dst + 4) = make_uint4(pk[4], pk[5], pk[6], pk[7]);
    }
}

// conv2: y1 (16ch) -> y2 (16ch) per branch.  Thread: 4 z-pos x 16 co.
// Weights staged in LDS fp32, 27-tap (one dw-slice) chunks: 27*16*16*4 = 27.6 KB.
__global__ __launch_bounds__(256) void conv2_kernel(
    const uint32_t* __restrict__ y1, const float* __restrict__ Wp2,
    const float* __restrict__ b2, uint32_t* __restrict__ y2) {
    __shared__ float Wl[27 * 256];
    const int tid = threadIdx.x, idx = blockIdx.x;
    const int pgblk = idx % 324, br = (idx / 324) & 1, n = idx / 648;
    const int pg = pgblk * 256 + tid;
    const int zb = (pg % 6) * 4, y = (pg / 6) % 24, xx = (pg / 144) % 24, w = pg / 3456;
    const uint32_t* inb = y1 + (size_t)(n * 2 + br) * S4 * 8;

    float acc[64];
#pragma unroll
    for (int i = 0; i < 64; ++i) acc[i] = 0.f;

#pragma unroll 1
    for (int dw = 0; dw < 3; ++dw) {
        __syncthreads();
        for (int i = tid; i < 27 * 256; i += 256)
            Wl[i] = Wp2[br * 81 * 256 + dw * 27 * 256 + i];
        __syncthreads();
        int wsrc = w + dw - 1; bool okw = (unsigned)wsrc < 24u;
#pragma unroll 1
        for (int dx = 0; dx < 3; ++dx) {
            int xsrc = xx + dx - 1; bool okx = okw && (unsigned)xsrc < 24u;
#pragma unroll 1
            for (int dy = 0; dy < 3; ++dy) {
                int ysrc = y + dy - 1; bool oky = okx && (unsigned)ysrc < 24u;
                int rowb = wsrc * S3 + xsrc * S2 + ysrc * S;
#pragma unroll 1
                for (int dz = 0; dz < 3; ++dz) {
                    int tl = dx * 9 + dy * 3 + dz;     // local tap in dw-chunk
                    uint32_t a[4][8];
#pragma unroll
                    for (int j = 0; j < 4; ++j) {
                        int zsrc = zb + j + dz - 1;
                        bool ok = oky && (unsigned)zsrc < 24u;
                        if (ok) {
                            const uint32_t* p = inb + (size_t)(rowb + zsrc) * 8;
                            uint4 u0 = *(const uint4*)(p);
                            uint4 u1 = *(const uint4*)(p + 4);
                            a[j][0] = u0.x; a[j][1] = u0.y; a[j][2] = u0.z; a[j][3] = u0.w;
                            a[j][4] = u1.x; a[j][5] = u1.y; a[j][6] = u1.z; a[j][7] = u1.w;
                        } else {
#pragma unroll
                            for (int q = 0; q < 8; ++q) a[j][q] = 0u;
                        }
                    }
                    const float* wt = &Wl[tl * 256];
#pragma unroll
                    for (int ci = 0; ci < 16; ++ci) {
                        float xf[4];
#pragma unroll
                        for (int j = 0; j < 4; ++j) {
                            uint32_t u = a[j][ci >> 1];
                            xf[j] = (ci & 1) ? bfhi(u) : bflo(u);
                        }
#pragma unroll
                        for (int co = 0; co < 16; ++co) {
                            float wv = wt[ci * 16 + co];
#pragma unroll
                            for (int j = 0; j < 4; ++j)
                                acc[j * 16 + co] = fmaf(xf[j], wv, acc[j * 16 + co]);
                        }
                    }
                }
            }
        }
    }
    uint32_t* yb = y2 + (size_t)(n * 2 + br) * S4 * 8;
    const int pos = w * S3 + xx * S2 + y * S + zb;
#pragma unroll
    for (int j = 0; j < 4; ++j) {
        uint32_t pk[8];
#pragma unroll
        for (int cp = 0; cp < 8; ++cp) {
            float a = fmaxf(acc[j * 16 + 2 * cp]     + b2[2 * cp],     0.f);
            float b = fmaxf(acc[j * 16 + 2 * cp + 1] + b2[2 * cp + 1], 0.f);
            pk[cp] = f2bf(a) | (f2bf(b) << 16);
        }
        uint32_t* dst = yb + (size_t)(pos + j) * 8;
        *(uint4*)(dst)     = make_uint4(pk[0], pk[1], pk[2], pk[3]);
        *(uint4*)(dst + 4) = make_uint4(pk[4], pk[5], pk[6], pk[7]);
    }
}

// conv3: y2 (16ch, both branches) -> out fp32.  out = relu(A+b3) + relu(B+b3).
__global__ __launch_bounds__(256) void conv3_kernel(
    const uint32_t* __restrict__ y2, const float* __restrict__ Wp3,
    const float* __restrict__ b3, float* __restrict__ out) {
    __shared__ float Wl[2 * 81 * 16];
    const int tid = threadIdx.x, idx = blockIdx.x;
    const int pgblk = idx % 324, n = idx / 324;
    for (int i = tid; i < 2 * 81 * 16; i += 256) Wl[i] = Wp3[i];
    __syncthreads();
    const int pg = pgblk * 256 + tid;
    const int zb = (pg % 6) * 4, y = (pg / 6) % 24, xx = (pg / 144) % 24, w = pg / 3456;
    const uint32_t* ib0 = y2 + (size_t)(n * 2 + 0) * S4 * 8;
    const uint32_t* ib1 = y2 + (size_t)(n * 2 + 1) * S4 * 8;

    float acc[2][4];
#pragma unroll
    for (int b = 0; b < 2; ++b)
#pragma unroll
        for (int j = 0; j < 4; ++j) acc[b][j] = 0.f;

#pragma unroll 1
    for (int dw = 0; dw < 3; ++dw) {
        int wsrc = w + dw - 1; bool okw = (unsigned)wsrc < 24u;
#pragma unroll 1
        for (int dx = 0; dx < 3; ++dx) {
            int xsrc = xx + dx - 1; bool okx = okw && (unsigned)xsrc < 24u;
#pragma unroll 1
            for (int dy = 0; dy < 3; ++dy) {
                int ysrc = y + dy - 1; bool oky = okx && (unsigned)ysrc < 24u;
                int rowb = wsrc * S3 + xsrc * S2 + ysrc * S;
#pragma unroll 1
                for (int dz = 0; dz < 3; ++dz) {
                    int t = dw * 27 + dx * 9 + dy * 3 + dz;
#pragma unroll
                    for (int b = 0; b < 2; ++b) {
                        const uint32_t* ib = b ? ib1 : ib0;
                        const float* wt = &Wl[(b * 81 + t) * 16];
#pragma unroll
                        for (int j = 0; j < 4; ++j) {
                            int zsrc = zb + j + dz - 1;
                            bool ok = oky && (unsigned)zsrc < 24u;
                            uint32_t a[8];
                            if (ok) {
                                const uint32_t* p = ib + (size_t)(rowb + zsrc) * 8;
                                uint4 u0 = *(const uint4*)(p);
                                uint4 u1 = *(const uint4*)(p + 4);
                                a[0]=u0.x; a[1]=u0.y; a[2]=u0.z; a[3]=u0.w;
                                a[4]=u1.x; a[5]=u1.y; a[6]=u1.z; a[7]=u1.w;
                            } else {
#pragma unroll
                                for (int q = 0; q < 8; ++q) a[q] = 0u;
                            }
                            float s = acc[b][j];
#pragma unroll
                            for (int cp = 0; cp < 8; ++cp) {
                                s = fmaf(bflo(a[cp]), wt[2 * cp],     s);
                                s = fmaf(bfhi(a[cp]), wt[2 * cp + 1], s);
                            }
                            acc[b][j] = s;
                        }
                    }
                }
            }
        }
    }
    const float bias = b3[0];
    float* ob = out + (size_t)n * S4;
    const int pos = w * S3 + xx * S2 + y * S + zb;
#pragma unroll
    for (int j = 0; j < 4; ++j)
        ob[pos + j] = fmaxf(acc[0][j] + bias, 0.f) + fmaxf(acc[1][j] + bias, 0.f);
}

extern "C" void kernel_launch(void* const* d_in, const int* in_sizes, int n_in,
                              void* d_out, int out_size, void* d_ws, size_t ws_size,
                              hipStream_t stream) {
    const float* x  = (const float*)d_in[0];
    const float* w1 = (const float*)d_in[1];
    const float* b1 = (const float*)d_in[2];
    const float* w2 = (const float*)d_in[3];
    const float* b2 = (const float*)d_in[4];
    const float* w3 = (const float*)d_in[5];
    const float* b3 = (const float*)d_in[6];
    float* out = (float*)d_out;
    char* ws = (char*)d_ws;

    float* Wp1 = (float*)(ws);              // 81*32*4      = 10368 B
    float* Wp2 = (float*)(ws + 12288);      // 2*81*256*4   = 165888 B
    float* Wp3 = (float*)(ws + 178176);     // 2*81*16*4    = 10368 B
    const size_t WEND = 196608;
    const size_t YSZ1 = (size_t)2 * S4 * 16 * 2;   // bf16 bytes per n per tensor

    prep_weights<<<1, 256, 0, stream>>>(w1, w2, w3, Wp1, Wp2, Wp3);

    if (ws_size >= WEND + 16 * YSZ1) {
        // full batch in one pass
        uint32_t* y1 = (uint32_t*)(ws + WEND);
        uint32_t* y2 = (uint32_t*)(ws + WEND + 8 * YSZ1);
        conv1_kernel<<<dim3(8 * 2 * 324), dim3(256), 0, stream>>>(x, Wp1, b1, y1);
        conv2_kernel<<<dim3(8 * 2 * 324), dim3(256), 0, stream>>>(y1, Wp2, b2, y2);
        conv3_kernel<<<dim3(8 * 324),     dim3(256), 0, stream>>>(y2, Wp3, b3, out);
    } else {
        // per-batch-item fallback (needs ~41 MB of workspace)
        uint32_t* y1 = (uint32_t*)(ws + WEND);
        uint32_t* y2 = (uint32_t*)(ws + WEND + YSZ1);
        for (int n = 0; n < 8; ++n) {
            conv1_kernel<<<dim3(648), dim3(256), 0, stream>>>(x + (size_t)n * S4, Wp1, b1, y1);
            conv2_kernel<<<dim3(648), dim3(256), 0, stream>>>(y1, Wp2, b2, y2);
            conv3_kernel<<<dim3(324), dim3(256), 0, stream>>>(y2, Wp3, b3, out + (size_t)n * S4);
        }
    }
}